// Round 9
// baseline (234.121 us; speedup 1.0000x reference)
//
#include <hip/hip_runtime.h>
#include <hip/hip_bf16.h>
#include <stdint.h>

#define N_ROWS 8192
#define DIM    1024
#define BM 128
#define BN 128
#define BKF 128            // fp8 bytes of K per tile (= one MFMA K)
#define NT (DIM / BKF)     // 8 K-tiles per C-tile
#define TILES_PB 8         // B-tiles per block (F-amortization)
#define VSTEPS (NT * TILES_PB)   // 64 virtual K-steps per block
#define NBLK (N_ROWS / BM * N_ROWS / BN / TILES_PB)   // 512 sim blocks

typedef float   f32x4  __attribute__((ext_vector_type(4)));
typedef int     i32x4  __attribute__((ext_vector_type(4)));
typedef int     i32x8  __attribute__((ext_vector_type(8)));

// 16-lane (DPP row) sum via v_add_f32 + row_ror — no LDS traffic.
__device__ __forceinline__ float row_sum16(float x) {
    x += __int_as_float(__builtin_amdgcn_update_dpp(
            0, __float_as_int(x), 0x128 /*row_ror:8*/, 0xf, 0xf, true));
    x += __int_as_float(__builtin_amdgcn_update_dpp(
            0, __float_as_int(x), 0x124 /*row_ror:4*/, 0xf, 0xf, true));
    x += __int_as_float(__builtin_amdgcn_update_dpp(
            0, __float_as_int(x), 0x122 /*row_ror:2*/, 0xf, 0xf, true));
    x += __int_as_float(__builtin_amdgcn_update_dpp(
            0, __float_as_int(x), 0x121 /*row_ror:1*/, 0xf, 0xf, true));
    return x;
}

// ---------------------------------------------------------------------------
// Kernel 1: L2-normalize + fp8 cast + diagonal + S/cnt init.
// REWRITTEN: one WAVE per row (was one block per 8 rows with 16 barriers).
// Zero __syncthreads, zero LDS; 2048 blocks x 4 waves; ~BW-floor target.
// Lane l holds float4 chunks l+64j (j=0..3) of its row: all loads/stores
// stay perfectly coalesced (64 consecutive float4 per instruction).
// ---------------------------------------------------------------------------
__global__ __launch_bounds__(256) void nrm_kernel(
    const float* __restrict__ img, const float* __restrict__ txt,
    uint8_t* __restrict__ img_f8, uint8_t* __restrict__ txt_f8,
    float* __restrict__ diag, float* __restrict__ S, int* __restrict__ cnt)
{
    const int t    = threadIdx.x;
    const int lane = t & 63;
    const int wv   = t >> 6;
    const int row  = blockIdx.x * 4 + wv;

    const float4* ip = (const float4*)(img + (size_t)row * DIM);
    const float4* tp = (const float4*)(txt + (size_t)row * DIM);

    float4 a[4], b[4];
    float sa = 0.f, sb = 0.f, dp = 0.f;
#pragma unroll
    for (int j = 0; j < 4; ++j) {
        a[j] = ip[lane + 64 * j];
        b[j] = tp[lane + 64 * j];
        sa += a[j].x * a[j].x + a[j].y * a[j].y + a[j].z * a[j].z + a[j].w * a[j].w;
        sb += b[j].x * b[j].x + b[j].y * b[j].y + b[j].z * b[j].z + b[j].w * b[j].w;
        dp += a[j].x * b[j].x + a[j].y * b[j].y + a[j].z * b[j].z + a[j].w * b[j].w;
    }
#pragma unroll
    for (int d = 1; d < 64; d <<= 1) {
        sa += __shfl_xor(sa, d, 64);
        sb += __shfl_xor(sb, d, 64);
        dp += __shfl_xor(dp, d, 64);
    }

    const float ia = 1.0f / fmaxf(sqrtf(sa), 1e-12f);
    const float ib = 1.0f / fmaxf(sqrtf(sb), 1e-12f);

#pragma unroll
    for (int j = 0; j < 4; ++j) {
        int ra = 0, rb = 0;
        ra = __builtin_amdgcn_cvt_pk_fp8_f32(a[j].x * ia, a[j].y * ia, ra, false);
        ra = __builtin_amdgcn_cvt_pk_fp8_f32(a[j].z * ia, a[j].w * ia, ra, true);
        rb = __builtin_amdgcn_cvt_pk_fp8_f32(b[j].x * ib, b[j].y * ib, rb, false);
        rb = __builtin_amdgcn_cvt_pk_fp8_f32(b[j].z * ib, b[j].w * ib, rb, true);
        ((int*)(img_f8 + (size_t)row * DIM))[lane + 64 * j] = ra;
        ((int*)(txt_f8 + (size_t)row * DIM))[lane + 64 * j] = rb;
    }

    if (lane == 0) {
        diag[row] = dp * ia * ib;   // normalized diagonal (linearity)
        S[row] = 0.0f;
        if (row == 0) *cnt = 0;     // reset completion counter each launch
    }
}

// ---------------------------------------------------------------------------
// Kernel 2: 128x128 MX-fp8 GEMM, multi-tile blocks + low-VALU K-step (R8,
// core byte-identical).  Changes this round:
//   (a) GRID AXES SWAPPED: blockIdx.x = A-panel (64), y = B-group (8).
//       Round-robin id->XCD gives each XCD ~8 distinct A panels (1 MB,
//       L2-resident; was 64 panels = 8 MB thrashing to L3 -> FETCH 262 MB)
//       and 8 same-group blocks walking one B-group in lockstep order.
//   (b) fin FUSED: last block (device atomic counter + threadfence) computes
//       mean(log S - diag) with agent-scope atomic loads (XCD-coherent).
// ---------------------------------------------------------------------------
__global__ __launch_bounds__(256) void sim_lse_kernel(
    const uint8_t* __restrict__ A, const uint8_t* __restrict__ B,
    float* __restrict__ S, const float* __restrict__ diag,
    float* __restrict__ out, int* __restrict__ cnt)
{
    __shared__ __align__(16) uint8_t smem[2 * 2 * BM * BKF];   // 64 KiB
    __shared__ int lastblk;
    __shared__ float fred[4];

    const int t     = threadIdx.x;       // 0..255
    const int lane  = t & 63;
    const int w     = t >> 6;            // wave 0..3
    const int waveM = w >> 1;            // 2x2 wave grid, 64x64 each
    const int waveN = w & 1;
    const int lr    = lane & 15;
    const int q     = lane >> 4;
    const int swz   = lr & 7;

    const int rowA0 = blockIdx.x * BM;                    // A panel (0..63)
    const uint8_t* Ablk = A + (size_t)rowA0 * DIM;
    const uint8_t* Bgrp = B + (size_t)blockIdx.y * TILES_PB * BN * DIM;

    const uint32_t lo_off = (uint32_t)(((2 * q) ^ swz) * 16);

    // ---- staging pointers: init ONCE, then uniform-delta advance ----------
    const uint8_t* pA[4];
    const uint8_t* pB[4];
    uint32_t ldsA[4], ldsB[4];
#pragma unroll
    for (int is = 0; is < 4; ++is) {
        const int c   = is * 256 + t;        // 16B chunk id, 0..1023
        const int row = c >> 3;              // 0..127
        const int col = (c & 7) ^ (row & 7); // pre-swizzled source chunk
        pA[is] = Ablk + (size_t)row * DIM + col * 16;
        pB[is] = Bgrp + (size_t)row * DIM + col * 16;
        ldsA[is] = (uint32_t)c * 16;
        ldsB[is] = 16384u + (uint32_t)c * 16;
    }

    auto stage_inc = [&](uint32_t ldsbase) {
#pragma unroll
        for (int is = 0; is < 4; ++is) {
            __builtin_amdgcn_global_load_lds(
                (const __attribute__((address_space(1))) void*)pA[is],
                (__attribute__((address_space(3))) void*)&smem[ldsbase + ldsA[is]],
                16, 0, 0);
            __builtin_amdgcn_global_load_lds(
                (const __attribute__((address_space(1))) void*)pB[is],
                (__attribute__((address_space(3))) void*)&smem[ldsbase + ldsB[is]],
                16, 0, 0);
        }
    };

    // ---- ds_read address registers (buffer toggle via XOR) ----------------
    uint32_t adrA  = (uint32_t)((waveM * 64 + lr) * BKF) + lo_off;
    uint32_t adrAh = (uint32_t)((waveM * 64 + lr) * BKF) + (lo_off ^ 16u);
    uint32_t adrB  = 16384u + (uint32_t)((waveN * 64 + lr) * BKF) + lo_off;
    uint32_t adrBh = 16384u + (uint32_t)((waveN * 64 + lr) * BKF) + (lo_off ^ 16u);

    f32x4 acc[4][4] = {};

    // ---- prologue ---------------------------------------------------------
    stage_inc(0u);
#pragma unroll
    for (int is = 0; is < 4; ++is) { pA[is] += 128; pB[is] += 128; }
    asm volatile("s_waitcnt vmcnt(0)" ::: "memory");
    __builtin_amdgcn_s_barrier();

    const float L2E = 1.44269504088896f;
    const int rowbase = rowA0 + waveM * 64;

    // ---- main loop: 64 virtual K-steps, continuous pipeline ---------------
#pragma unroll 1
    for (int v = 0; v < VSTEPS; ++v) {
        const uint32_t nxt = (uint32_t)(((v & 1) ^ 1) << 15);

        if (v < VSTEPS - 1) {
            stage_inc(nxt);                       // issue, don't wait
            const bool wrap = ((v + 1) & (NT - 1)) == (NT - 1);
            const int dA = wrap ? -(BKF * (NT - 1)) : BKF;              // -896 | +128
            const int dB = wrap ? (BN * DIM - BKF * (NT - 1)) : BKF;    // +130176 | +128
#pragma unroll
            for (int is = 0; is < 4; ++is) { pA[is] += dA; pB[is] += dB; }
        }

        i32x8 af[4], bfr[4];
#pragma unroll
        for (int mi = 0; mi < 4; ++mi) {
            i32x4 lo = *(const i32x4*)&smem[adrA  + mi * 2048];
            i32x4 hi = *(const i32x4*)&smem[adrAh + mi * 2048];
            af[mi] = __builtin_shufflevector(lo, hi, 0, 1, 2, 3, 4, 5, 6, 7);
        }
#pragma unroll
        for (int ni = 0; ni < 4; ++ni) {
            i32x4 lo = *(const i32x4*)&smem[adrB  + ni * 2048];
            i32x4 hi = *(const i32x4*)&smem[adrBh + ni * 2048];
            bfr[ni] = __builtin_shufflevector(lo, hi, 0, 1, 2, 3, 4, 5, 6, 7);
        }
#pragma unroll
        for (int mi = 0; mi < 4; ++mi)
#pragma unroll
            for (int ni = 0; ni < 4; ++ni)
                acc[mi][ni] = __builtin_amdgcn_mfma_scale_f32_16x16x128_f8f6f4(
                    af[mi], bfr[ni], acc[mi][ni],
                    0 /*fmtA=fp8*/, 0 /*fmtB=fp8*/,
                    0, 127 /*scaleA=1.0*/, 0, 127 /*scaleB=1.0*/);

        adrA ^= 32768u; adrAh ^= 32768u; adrB ^= 32768u; adrBh ^= 32768u;

        if ((v & (NT - 1)) == NT - 1) {   // tile finished: fused epilogue
#pragma unroll
            for (int mi = 0; mi < 4; ++mi) {
                float p0 = 0.f, p1 = 0.f, p2 = 0.f, p3 = 0.f;
#pragma unroll
                for (int ni = 0; ni < 4; ++ni) {
                    p0 += exp2f(acc[mi][ni].x * L2E - L2E);
                    p1 += exp2f(acc[mi][ni].y * L2E - L2E);
                    p2 += exp2f(acc[mi][ni].z * L2E - L2E);
                    p3 += exp2f(acc[mi][ni].w * L2E - L2E);
                    acc[mi][ni] = (f32x4){0.f, 0.f, 0.f, 0.f};
                }
                p0 = row_sum16(p0); p1 = row_sum16(p1);
                p2 = row_sum16(p2); p3 = row_sum16(p3);
                if ((lane & 15) == 0) {
                    float* dst = &S[rowbase + mi * 16 + (lane >> 4) * 4];
                    atomicAdd(dst + 0, p0); atomicAdd(dst + 1, p1);
                    atomicAdd(dst + 2, p2); atomicAdd(dst + 3, p3);
                }
            }
        }

        asm volatile("s_waitcnt vmcnt(0)" ::: "memory");
        __builtin_amdgcn_s_barrier();
    }

    // ---- fused finalizer: last block computes mean(log S - diag) ----------
    __threadfence();          // order this block's S atomics before cnt
    __syncthreads();          // all waves' atomics issued+fenced
    if (t == 0) lastblk = (atomicAdd(cnt, 1) == NBLK - 1);
    __syncthreads();
    if (lastblk) {
        float s = 0.f;
        for (int i = t; i < N_ROWS; i += 256) {
            const float sv = __hip_atomic_load(&S[i], __ATOMIC_RELAXED,
                                               __HIP_MEMORY_SCOPE_AGENT);
            s += logf(sv) - diag[i];
        }
#pragma unroll
        for (int d = 1; d < 64; d <<= 1) s += __shfl_xor(s, d, 64);
        if ((t & 63) == 0) fred[t >> 6] = s;
        __syncthreads();
        if (t == 0)
            out[0] = (fred[0] + fred[1] + fred[2] + fred[3]) * (1.0f / N_ROWS);
    }
}

// ---------------------------------------------------------------------------
extern "C" void kernel_launch(void* const* d_in, const int* in_sizes, int n_in,
                              void* d_out, int out_size, void* d_ws, size_t ws_size,
                              hipStream_t stream)
{
    const float* img = (const float*)d_in[0];
    const float* txt = (const float*)d_in[1];
    float* out = (float*)d_out;

    char* ws = (char*)d_ws;
    uint8_t* img_f8 = (uint8_t*)ws;                                  // 8 MiB
    uint8_t* txt_f8 = (uint8_t*)(ws + (size_t)N_ROWS * DIM);         // 8 MiB
    float*   S      = (float*)(ws + (size_t)N_ROWS * DIM * 2);       // 32 KiB
    float*   diag   = S + N_ROWS;                                    // 32 KiB
    int*     cnt    = (int*)(diag + N_ROWS);                         // 4 B

    nrm_kernel<<<N_ROWS / 4, 256, 0, stream>>>(img, txt, img_f8, txt_f8,
                                               diag, S, cnt);
    dim3 grid(N_ROWS / BM, N_ROWS / BN / TILES_PB);   // 64 panels x 8 groups
    sim_lse_kernel<<<grid, 256, 0, stream>>>(img_f8, txt_f8, S, diag, out, cnt);
}

// Round 10
// 187.778 us; speedup vs baseline: 1.2468x; 1.2468x over previous
//
#include <hip/hip_runtime.h>
#include <hip/hip_bf16.h>
#include <stdint.h>

#define N_ROWS 8192
#define DIM    1024
#define BM 128
#define BN 128
#define BKF 128            // fp8 bytes of K per tile (= one MFMA K)
#define NT (DIM / BKF)     // 8 K-tiles per C-tile
#define TILES_PB 8         // B-tiles per block (F-amortization)
#define VSTEPS (NT * TILES_PB)   // 64 virtual K-steps per block

typedef float   f32x4  __attribute__((ext_vector_type(4)));
typedef int     i32x4  __attribute__((ext_vector_type(4)));
typedef int     i32x8  __attribute__((ext_vector_type(8)));

// 16-lane (DPP row) sum via v_add_f32 + row_ror — no LDS traffic.
__device__ __forceinline__ float row_sum16(float x) {
    x += __int_as_float(__builtin_amdgcn_update_dpp(
            0, __float_as_int(x), 0x128 /*row_ror:8*/, 0xf, 0xf, true));
    x += __int_as_float(__builtin_amdgcn_update_dpp(
            0, __float_as_int(x), 0x124 /*row_ror:4*/, 0xf, 0xf, true));
    x += __int_as_float(__builtin_amdgcn_update_dpp(
            0, __float_as_int(x), 0x122 /*row_ror:2*/, 0xf, 0xf, true));
    x += __int_as_float(__builtin_amdgcn_update_dpp(
            0, __float_as_int(x), 0x121 /*row_ror:1*/, 0xf, 0xf, true));
    return x;
}

// ---------------------------------------------------------------------------
// Kernel 1: L2-normalize + fp8 cast + diagonal + S init.
// R9's wave-per-row structure (zero barriers, zero LDS), kept.
// ---------------------------------------------------------------------------
__global__ __launch_bounds__(256) void nrm_kernel(
    const float* __restrict__ img, const float* __restrict__ txt,
    uint8_t* __restrict__ img_f8, uint8_t* __restrict__ txt_f8,
    float* __restrict__ diag, float* __restrict__ S)
{
    const int t    = threadIdx.x;
    const int lane = t & 63;
    const int wv   = t >> 6;
    const int row  = blockIdx.x * 4 + wv;

    const float4* ip = (const float4*)(img + (size_t)row * DIM);
    const float4* tp = (const float4*)(txt + (size_t)row * DIM);

    float4 a[4], b[4];
    float sa = 0.f, sb = 0.f, dp = 0.f;
#pragma unroll
    for (int j = 0; j < 4; ++j) {
        a[j] = ip[lane + 64 * j];
        b[j] = tp[lane + 64 * j];
        sa += a[j].x * a[j].x + a[j].y * a[j].y + a[j].z * a[j].z + a[j].w * a[j].w;
        sb += b[j].x * b[j].x + b[j].y * b[j].y + b[j].z * b[j].z + b[j].w * b[j].w;
        dp += a[j].x * b[j].x + a[j].y * b[j].y + a[j].z * b[j].z + a[j].w * b[j].w;
    }
#pragma unroll
    for (int d = 1; d < 64; d <<= 1) {
        sa += __shfl_xor(sa, d, 64);
        sb += __shfl_xor(sb, d, 64);
        dp += __shfl_xor(dp, d, 64);
    }

    const float ia = 1.0f / fmaxf(sqrtf(sa), 1e-12f);
    const float ib = 1.0f / fmaxf(sqrtf(sb), 1e-12f);

#pragma unroll
    for (int j = 0; j < 4; ++j) {
        int ra = 0, rb = 0;
        ra = __builtin_amdgcn_cvt_pk_fp8_f32(a[j].x * ia, a[j].y * ia, ra, false);
        ra = __builtin_amdgcn_cvt_pk_fp8_f32(a[j].z * ia, a[j].w * ia, ra, true);
        rb = __builtin_amdgcn_cvt_pk_fp8_f32(b[j].x * ib, b[j].y * ib, rb, false);
        rb = __builtin_amdgcn_cvt_pk_fp8_f32(b[j].z * ib, b[j].w * ib, rb, true);
        ((int*)(img_f8 + (size_t)row * DIM))[lane + 64 * j] = ra;
        ((int*)(txt_f8 + (size_t)row * DIM))[lane + 64 * j] = rb;
    }

    if (lane == 0) {
        diag[row] = dp * ia * ib;   // normalized diagonal (linearity)
        S[row] = 0.0f;
    }
}

// ---------------------------------------------------------------------------
// Kernel 2: 128x128 MX-fp8 GEMM — REVERTED byte-exact to R8 (session-best
// sim: 104.7us, MfmaUtil 27%).  R9's axis swap + fence/finalizer regressed it
// to 152us despite FETCH 262->37 MB: locality was never the limiter (R8's
// 2.7 TB/s HBM stream was fully pipeline-hidden).  Grid: x=B-group (8),
// y=A-panel (64).  Multi-tile blocks (64 vsteps), dist-1 dbuf, XOR chunk
// swizzle, incremental uniform-delta staging pointers, precomputed ds_read
// address regs + XOR buffer toggle, shufflevector frags, per-tile DPP
// row-sum epilogue overlapping in-flight staging, atomicAdd into S.
// ---------------------------------------------------------------------------
__global__ __launch_bounds__(256) void sim_lse_kernel(
    const uint8_t* __restrict__ A, const uint8_t* __restrict__ B,
    float* __restrict__ S)
{
    __shared__ __align__(16) uint8_t smem[2 * 2 * BM * BKF];   // 64 KiB

    const int t     = threadIdx.x;       // 0..255
    const int lane  = t & 63;
    const int w     = t >> 6;            // wave 0..3
    const int waveM = w >> 1;            // 2x2 wave grid, 64x64 each
    const int waveN = w & 1;
    const int lr    = lane & 15;
    const int q     = lane >> 4;
    const int swz   = lr & 7;

    const int rowA0 = blockIdx.y * BM;                    // A panel (0..63)
    const uint8_t* Ablk = A + (size_t)rowA0 * DIM;
    const uint8_t* Bgrp = B + (size_t)blockIdx.x * TILES_PB * BN * DIM;

    const uint32_t lo_off = (uint32_t)(((2 * q) ^ swz) * 16);

    // ---- staging pointers: init ONCE, then uniform-delta advance ----------
    const uint8_t* pA[4];
    const uint8_t* pB[4];
    uint32_t ldsA[4], ldsB[4];
#pragma unroll
    for (int is = 0; is < 4; ++is) {
        const int c   = is * 256 + t;        // 16B chunk id, 0..1023
        const int row = c >> 3;              // 0..127
        const int col = (c & 7) ^ (row & 7); // pre-swizzled source chunk
        pA[is] = Ablk + (size_t)row * DIM + col * 16;
        pB[is] = Bgrp + (size_t)row * DIM + col * 16;
        ldsA[is] = (uint32_t)c * 16;
        ldsB[is] = 16384u + (uint32_t)c * 16;
    }

    auto stage_inc = [&](uint32_t ldsbase) {
#pragma unroll
        for (int is = 0; is < 4; ++is) {
            __builtin_amdgcn_global_load_lds(
                (const __attribute__((address_space(1))) void*)pA[is],
                (__attribute__((address_space(3))) void*)&smem[ldsbase + ldsA[is]],
                16, 0, 0);
            __builtin_amdgcn_global_load_lds(
                (const __attribute__((address_space(1))) void*)pB[is],
                (__attribute__((address_space(3))) void*)&smem[ldsbase + ldsB[is]],
                16, 0, 0);
        }
    };

    // ---- ds_read address registers (buffer toggle via XOR) ----------------
    uint32_t adrA  = (uint32_t)((waveM * 64 + lr) * BKF) + lo_off;
    uint32_t adrAh = (uint32_t)((waveM * 64 + lr) * BKF) + (lo_off ^ 16u);
    uint32_t adrB  = 16384u + (uint32_t)((waveN * 64 + lr) * BKF) + lo_off;
    uint32_t adrBh = 16384u + (uint32_t)((waveN * 64 + lr) * BKF) + (lo_off ^ 16u);

    f32x4 acc[4][4] = {};

    // ---- prologue ---------------------------------------------------------
    stage_inc(0u);
#pragma unroll
    for (int is = 0; is < 4; ++is) { pA[is] += 128; pB[is] += 128; }
    asm volatile("s_waitcnt vmcnt(0)" ::: "memory");
    __builtin_amdgcn_s_barrier();

    const float L2E = 1.44269504088896f;
    const int rowbase = rowA0 + waveM * 64;

    // ---- main loop: 64 virtual K-steps, continuous pipeline ---------------
#pragma unroll 1
    for (int v = 0; v < VSTEPS; ++v) {
        const uint32_t nxt = (uint32_t)(((v & 1) ^ 1) << 15);

        if (v < VSTEPS - 1) {
            stage_inc(nxt);                       // issue, don't wait
            const bool wrap = ((v + 1) & (NT - 1)) == (NT - 1);
            const int dA = wrap ? -(BKF * (NT - 1)) : BKF;              // -896 | +128
            const int dB = wrap ? (BN * DIM - BKF * (NT - 1)) : BKF;    // +130176 | +128
#pragma unroll
            for (int is = 0; is < 4; ++is) { pA[is] += dA; pB[is] += dB; }
        }

        i32x8 af[4], bfr[4];
#pragma unroll
        for (int mi = 0; mi < 4; ++mi) {
            i32x4 lo = *(const i32x4*)&smem[adrA  + mi * 2048];
            i32x4 hi = *(const i32x4*)&smem[adrAh + mi * 2048];
            af[mi] = __builtin_shufflevector(lo, hi, 0, 1, 2, 3, 4, 5, 6, 7);
        }
#pragma unroll
        for (int ni = 0; ni < 4; ++ni) {
            i32x4 lo = *(const i32x4*)&smem[adrB  + ni * 2048];
            i32x4 hi = *(const i32x4*)&smem[adrBh + ni * 2048];
            bfr[ni] = __builtin_shufflevector(lo, hi, 0, 1, 2, 3, 4, 5, 6, 7);
        }
#pragma unroll
        for (int mi = 0; mi < 4; ++mi)
#pragma unroll
            for (int ni = 0; ni < 4; ++ni)
                acc[mi][ni] = __builtin_amdgcn_mfma_scale_f32_16x16x128_f8f6f4(
                    af[mi], bfr[ni], acc[mi][ni],
                    0 /*fmtA=fp8*/, 0 /*fmtB=fp8*/,
                    0, 127 /*scaleA=1.0*/, 0, 127 /*scaleB=1.0*/);

        adrA ^= 32768u; adrAh ^= 32768u; adrB ^= 32768u; adrBh ^= 32768u;

        if ((v & (NT - 1)) == NT - 1) {   // tile finished: fused epilogue
#pragma unroll
            for (int mi = 0; mi < 4; ++mi) {
                float p0 = 0.f, p1 = 0.f, p2 = 0.f, p3 = 0.f;
#pragma unroll
                for (int ni = 0; ni < 4; ++ni) {
                    p0 += exp2f(acc[mi][ni].x * L2E - L2E);
                    p1 += exp2f(acc[mi][ni].y * L2E - L2E);
                    p2 += exp2f(acc[mi][ni].z * L2E - L2E);
                    p3 += exp2f(acc[mi][ni].w * L2E - L2E);
                    acc[mi][ni] = (f32x4){0.f, 0.f, 0.f, 0.f};
                }
                p0 = row_sum16(p0); p1 = row_sum16(p1);
                p2 = row_sum16(p2); p3 = row_sum16(p3);
                if ((lane & 15) == 0) {
                    float* dst = &S[rowbase + mi * 16 + (lane >> 4) * 4];
                    atomicAdd(dst + 0, p0); atomicAdd(dst + 1, p1);
                    atomicAdd(dst + 2, p2); atomicAdd(dst + 3, p3);
                }
            }
        }

        asm volatile("s_waitcnt vmcnt(0)" ::: "memory");
        __builtin_amdgcn_s_barrier();
    }
}

// ---------------------------------------------------------------------------
// Kernel 3: out = mean(log(S_i) - diag_i)   (restored as its own dispatch)
// ---------------------------------------------------------------------------
__global__ __launch_bounds__(1024) void fin_kernel(
    const float* __restrict__ S, const float* __restrict__ diag,
    float* __restrict__ out)
{
    const int t = threadIdx.x;
    float s = 0.f;
    for (int i = t; i < N_ROWS; i += 1024) s += logf(S[i]) - diag[i];
#pragma unroll
    for (int d = 1; d < 64; d <<= 1) s += __shfl_xor(s, d, 64);
    __shared__ float red[16];
    if ((t & 63) == 0) red[t >> 6] = s;
    __syncthreads();
    if (t == 0) {
        float tot = 0.f;
#pragma unroll
        for (int i = 0; i < 16; ++i) tot += red[i];
        out[0] = tot * (1.0f / N_ROWS);
    }
}

// ---------------------------------------------------------------------------
extern "C" void kernel_launch(void* const* d_in, const int* in_sizes, int n_in,
                              void* d_out, int out_size, void* d_ws, size_t ws_size,
                              hipStream_t stream)
{
    const float* img = (const float*)d_in[0];
    const float* txt = (const float*)d_in[1];
    float* out = (float*)d_out;

    char* ws = (char*)d_ws;
    uint8_t* img_f8 = (uint8_t*)ws;                                  // 8 MiB
    uint8_t* txt_f8 = (uint8_t*)(ws + (size_t)N_ROWS * DIM);         // 8 MiB
    float*   S      = (float*)(ws + (size_t)N_ROWS * DIM * 2);       // 32 KiB
    float*   diag   = S + N_ROWS;                                    // 32 KiB

    nrm_kernel<<<N_ROWS / 4, 256, 0, stream>>>(img, txt, img_f8, txt_f8,
                                               diag, S);
    dim3 grid(N_ROWS / BN / TILES_PB, N_ROWS / BM);   // 8 groups x 64 panels
    sim_lse_kernel<<<grid, 256, 0, stream>>>(img_f8, txt_f8, S);
    fin_kernel<<<1, 1024, 0, stream>>>(S, diag, out);
}